// Round 2
// baseline (607.758 us; speedup 1.0000x reference)
//
#include <hip/hip_runtime.h>
#include <math.h>

#define BB 8
#define SS 512
#define VV 32000
#define ROWS (BB * SS)        // 4096
#define CHUNKS 4
#define CF4 2000              // float4s per chunk (row = 8000 float4s / 4 chunks)
#define UNITS (ROWS * CHUNKS) // 16384 work units of 32 KB
#define GRID1 2048            // persistent grid: ~8 blocks/CU, 8 units/block

typedef float f4 __attribute__((ext_vector_type(4)));

// Kernel 1: persistent grid-stride over (row, chunk) units. 2048 blocks
// instead of 16384 -> 14336 fewer workgroup dispatches; invalid units skip
// via an LDS-cached mask (no global load on the skip path). Per-wave partial
// sums store directly to ws[u*4 + wave] -- no cross-wave LDS reduction, no
// __syncthreads in the loop. Streaming loads are nontemporal (predict is
// read exactly once; don't thrash L2/L3 with dead lines).
__global__ __launch_bounds__(256) void chunk_sumexp_kernel(
    const float* __restrict__ predict,
    const int*   __restrict__ mask,
    float*       __restrict__ ws)
{
    const int tid = threadIdx.x;

    __shared__ int wls[BB];
    if (tid < BB) wls[tid] = mask[tid];
    __syncthreads();

    for (int u = blockIdx.x; u < UNITS; u += GRID1) {
        const int row = u >> 2;
        const int b   = row >> 9;
        const int s   = row & 511;
        if (s >= wls[b]) continue;          // block-uniform: no divergence

        const int chunk = u & 3;
        const f4* rp4 = (const f4*)(predict + (size_t)row * VV) + (size_t)chunk * CF4;

        // 8 loads in flight before any exp work (7 unconditional + 1
        // predicated; 2000 = 7*256 + 208) -> max memory-level parallelism.
        f4 v0 = __builtin_nontemporal_load(rp4 + tid);
        f4 v1 = __builtin_nontemporal_load(rp4 + tid + 256);
        f4 v2 = __builtin_nontemporal_load(rp4 + tid + 512);
        f4 v3 = __builtin_nontemporal_load(rp4 + tid + 768);
        f4 v4 = __builtin_nontemporal_load(rp4 + tid + 1024);
        f4 v5 = __builtin_nontemporal_load(rp4 + tid + 1280);
        f4 v6 = __builtin_nontemporal_load(rp4 + tid + 1536);
        float s7 = 0.0f;
        if (tid < CF4 - 7 * 256) {          // tid < 208
            f4 v7 = __builtin_nontemporal_load(rp4 + tid + 1792);
            s7 = __expf(v7.x) + __expf(v7.y) + __expf(v7.z) + __expf(v7.w);
        }

        float sum = s7
            + __expf(v0.x) + __expf(v0.y) + __expf(v0.z) + __expf(v0.w)
            + __expf(v1.x) + __expf(v1.y) + __expf(v1.z) + __expf(v1.w)
            + __expf(v2.x) + __expf(v2.y) + __expf(v2.z) + __expf(v2.w)
            + __expf(v3.x) + __expf(v3.y) + __expf(v3.z) + __expf(v3.w)
            + __expf(v4.x) + __expf(v4.y) + __expf(v4.z) + __expf(v4.w)
            + __expf(v5.x) + __expf(v5.y) + __expf(v5.z) + __expf(v5.w)
            + __expf(v6.x) + __expf(v6.y) + __expf(v6.z) + __expf(v6.w);

        // wave(64) shuffle reduction; lane 0 of each wave stores its partial
        #pragma unroll
        for (int off = 32; off > 0; off >>= 1)
            sum += __shfl_down(sum, off, 64);

        if ((tid & 63) == 0)
            ws[u * 4 + (tid >> 6)] = sum;   // 16 partials per row, contiguous
    }
}

// Kernel 2: single block. All 16 target loads issue, then all 16 predict
// gathers (always in-bounds, masked rows discarded later), then the 64
// coalesced-ish float4 ws reads (256 KB total, mostly L2), then arithmetic.
__global__ __launch_bounds__(256) void finalize_kernel(
    const float* __restrict__ predict,
    const int*   __restrict__ target,
    const int*   __restrict__ mask,
    const float* __restrict__ ws,
    float*       __restrict__ out)
{
    const int tid = threadIdx.x;

    __shared__ int wls[BB];
    if (tid < BB) wls[tid] = mask[tid];
    __syncthreads();

    int   tg[ROWS / 256];
    float xt[ROWS / 256];
    float S [ROWS / 256];

    #pragma unroll
    for (int k = 0; k < ROWS / 256; ++k) {   // 16 rows per thread
        const int r = tid + k * 256;
        tg[k] = target[r];
    }

    #pragma unroll
    for (int k = 0; k < ROWS / 256; ++k) {   // long-latency scattered gathers
        const int r = tid + k * 256;
        xt[k] = predict[(size_t)r * VV + tg[k]];   // always in-bounds
    }

    #pragma unroll
    for (int k = 0; k < ROWS / 256; ++k) {   // 16 wave-partials per row
        const int r = tid + k * 256;
        const float4* wp = (const float4*)ws + r * 4;
        const float4 a = wp[0], b2 = wp[1], c = wp[2], d = wp[3];
        S[k] = ((a.x + a.y) + (a.z + a.w)) + ((b2.x + b2.y) + (b2.z + b2.w))
             + ((c.x + c.y) + (c.z + c.w)) + ((d.x + d.y) + (d.z + d.w));
    }

    float acc = 0.0f;
    #pragma unroll
    for (int k = 0; k < ROWS / 256; ++k) {
        const int r  = tid + k * 256;
        const int s  = r & 511;
        const int wl = wls[r >> 9];
        if (s < wl)
            acc += (__logf(S[k]) - xt[k]) / ((float)wl * (float)BB);
    }

    #pragma unroll
    for (int off = 32; off > 0; off >>= 1)
        acc += __shfl_down(acc, off, 64);

    __shared__ float ssum[4];
    if ((tid & 63) == 0) ssum[tid >> 6] = acc;
    __syncthreads();
    if (tid == 0)
        out[0] = ssum[0] + ssum[1] + ssum[2] + ssum[3];
}

extern "C" void kernel_launch(void* const* d_in, const int* in_sizes, int n_in,
                              void* d_out, int out_size, void* d_ws, size_t ws_size,
                              hipStream_t stream) {
    const float* predict = (const float*)d_in[0];
    const int*   target  = (const int*)  d_in[1];
    const int*   mask    = (const int*)  d_in[2];
    float* out = (float*)d_out;
    float* ws  = (float*)d_ws;

    chunk_sumexp_kernel<<<GRID1, 256, 0, stream>>>(predict, mask, ws);
    finalize_kernel<<<1, 256, 0, stream>>>(predict, target, mask, ws, out);
}

// Round 3
// 592.926 us; speedup vs baseline: 1.0250x; 1.0250x over previous
//
#include <hip/hip_runtime.h>
#include <math.h>

#define BB 8
#define SS 512
#define VV 32000
#define ROWS (BB * SS)        // 4096
#define CHUNKS 4
#define CF4 2000              // float4s per chunk
#define CFLT 8000             // floats per chunk
#define UNITS (ROWS * CHUNKS) // 16384
#define XT_OFF UNITS          // ws[XT_OFF + row] = predict[row*VV + target[row]]

typedef float f4 __attribute__((ext_vector_type(4)));

// Kernel 1: one block per (row, chunk) -- round-1 structure (the persistent
// grid variant measured +10us; HW dispatch of short blocks is free). Invalid
// rows exit before touching predict. Additionally extracts the target logit
// in-register: the thread that streamed column t writes it to ws[XT_OFF+row],
// so finalize never re-reads predict (whose lines we evict with nt loads).
__global__ __launch_bounds__(256) void chunk_sumexp_kernel(
    const float* __restrict__ predict,
    const int*   __restrict__ target,
    const int*   __restrict__ mask,
    float*       __restrict__ ws)
{
    const int bid   = blockIdx.x;
    const int row   = bid >> 2;
    const int chunk = bid & 3;
    const int b     = row >> 9;
    const int s     = row & 511;
    if (s >= mask[b]) return;

    const f4* rp4 = (const f4*)(predict + (size_t)row * VV) + (size_t)chunk * CF4;
    const int tid = threadIdx.x;

    // 8 loads in flight before any exp work (7 unconditional + 1 predicated;
    // 2000 = 7*256 + 208) -> max memory-level parallelism. Nontemporal:
    // predict is read exactly once per element, evict-first.
    f4 v0 = __builtin_nontemporal_load(rp4 + tid);
    f4 v1 = __builtin_nontemporal_load(rp4 + tid + 256);
    f4 v2 = __builtin_nontemporal_load(rp4 + tid + 512);
    f4 v3 = __builtin_nontemporal_load(rp4 + tid + 768);
    f4 v4 = __builtin_nontemporal_load(rp4 + tid + 1024);
    f4 v5 = __builtin_nontemporal_load(rp4 + tid + 1280);
    f4 v6 = __builtin_nontemporal_load(rp4 + tid + 1536);
    f4 v7 = {0.0f, 0.0f, 0.0f, 0.0f};
    if (tid < CF4 - 7 * 256)            // tid < 208
        v7 = __builtin_nontemporal_load(rp4 + tid + 1792);

    // Target-logit extraction: uniform scalar work, one active lane.
    const int t = target[row];          // uniform -> scalar load, L2-cached
    if ((t / CFLT) == chunk) {
        const int q     = t - chunk * CFLT;   // [0, 8000)
        const int f     = q >> 2;             // float4 index [0, 2000)
        const int j     = f >> 8;             // which of v0..v7
        const int owner = f & 255;            // which thread loaded it
        if (tid == owner) {
            f4 vj;
            switch (j) {
                case 0: vj = v0; break;
                case 1: vj = v1; break;
                case 2: vj = v2; break;
                case 3: vj = v3; break;
                case 4: vj = v4; break;
                case 5: vj = v5; break;
                case 6: vj = v6; break;
                default: vj = v7; break;
            }
            const int e = t & 3;
            const float xv = (e == 0) ? vj.x : (e == 1) ? vj.y
                           : (e == 2) ? vj.z : vj.w;
            ws[XT_OFF + row] = xv;
        }
    }

    float s7 = 0.0f;
    if (tid < CF4 - 7 * 256)
        s7 = __expf(v7.x) + __expf(v7.y) + __expf(v7.z) + __expf(v7.w);

    float sum = s7
        + __expf(v0.x) + __expf(v0.y) + __expf(v0.z) + __expf(v0.w)
        + __expf(v1.x) + __expf(v1.y) + __expf(v1.z) + __expf(v1.w)
        + __expf(v2.x) + __expf(v2.y) + __expf(v2.z) + __expf(v2.w)
        + __expf(v3.x) + __expf(v3.y) + __expf(v3.z) + __expf(v3.w)
        + __expf(v4.x) + __expf(v4.y) + __expf(v4.z) + __expf(v4.w)
        + __expf(v5.x) + __expf(v5.y) + __expf(v5.z) + __expf(v5.w)
        + __expf(v6.x) + __expf(v6.y) + __expf(v6.z) + __expf(v6.w);

    // wave(64) shuffle reduction
    #pragma unroll
    for (int off = 32; off > 0; off >>= 1)
        sum += __shfl_down(sum, off, 64);

    // cross-wave reduction (4 waves)
    __shared__ float ssum[4];
    if ((tid & 63) == 0) ssum[tid >> 6] = sum;
    __syncthreads();
    if (tid == 0)
        ws[bid] = ssum[0] + ssum[1] + ssum[2] + ssum[3];
}

// Kernel 2: single block, touches ONLY ws (80 KB) + mask. All loads batch-
// issued (2 latency waves), then arithmetic. Invalid rows read garbage/poison
// but are discarded by branch (never multiplied -- NaN-safe).
__global__ __launch_bounds__(256) void finalize_kernel(
    const int*   __restrict__ mask,
    const float* __restrict__ ws,
    float*       __restrict__ out)
{
    const int tid = threadIdx.x;

    __shared__ int wls[BB];
    if (tid < BB) wls[tid] = mask[tid];
    __syncthreads();

    float4 w4[ROWS / 256];
    float  xt[ROWS / 256];

    #pragma unroll
    for (int k = 0; k < ROWS / 256; ++k) {   // 16 rows per thread, coalesced
        const int r = tid + k * 256;
        w4[k] = ((const float4*)ws)[r];      // 4 chunk partials
        xt[k] = ws[XT_OFF + r];              // target logit
    }

    float acc = 0.0f;
    #pragma unroll
    for (int k = 0; k < ROWS / 256; ++k) {
        const int r  = tid + k * 256;
        const int s  = r & 511;
        const int wl = wls[r >> 9];
        if (s < wl) {
            const float4 p = w4[k];
            const float  S = (p.x + p.y) + (p.z + p.w);
            acc += (__logf(S) - xt[k]) / ((float)wl * (float)BB);
        }
    }

    #pragma unroll
    for (int off = 32; off > 0; off >>= 1)
        acc += __shfl_down(acc, off, 64);

    __shared__ float ssum[4];
    if ((tid & 63) == 0) ssum[tid >> 6] = acc;
    __syncthreads();
    if (tid == 0)
        out[0] = ssum[0] + ssum[1] + ssum[2] + ssum[3];
}

extern "C" void kernel_launch(void* const* d_in, const int* in_sizes, int n_in,
                              void* d_out, int out_size, void* d_ws, size_t ws_size,
                              hipStream_t stream) {
    const float* predict = (const float*)d_in[0];
    const int*   target  = (const int*)  d_in[1];
    const int*   mask    = (const int*)  d_in[2];
    float* out = (float*)d_out;
    float* ws  = (float*)d_ws;

    chunk_sumexp_kernel<<<ROWS * CHUNKS, 256, 0, stream>>>(predict, target, mask, ws);
    finalize_kernel<<<1, 256, 0, stream>>>(mask, ws, out);
}